// Round 1
// baseline (471.869 us; speedup 1.0000x reference)
//
#include <hip/hip_runtime.h>
#include <math.h>

#define RDIM 256
#define CIN 64
#define COUT 64
#define MODES 16
#define NB 8

typedef short short8 __attribute__((ext_vector_type(8)));
typedef float f32x4 __attribute__((ext_vector_type(4)));

// f32 -> bf16 bits, round-to-nearest-even
__device__ __forceinline__ unsigned short f2b(float f) {
    unsigned u = __builtin_bit_cast(unsigned, f);
    unsigned r = (u + 0x7FFFu + ((u >> 16) & 1u)) >> 16;
    return (unsigned short)r;
}

// cos/sin table: tab[p] = (cos(2*pi*p/256), sin(2*pi*p/256))
__device__ __forceinline__ void build_tab(float2* tab) {
    for (int p = (int)threadIdx.x; p < 256; p += (int)blockDim.x) {
        float ang = (float)p * (float)(2.0 * M_PI / 256.0);
        float s, c;
        sincosf(ang, &s, &c);
        tab[p] = make_float2(c, s);
    }
}

// ---------------------------------------------------------------------------
// k_wt: transpose weights fw0/fw1 [i,o,mx,ky,2] -> WT[m(32)][ky(16)][i(64)][o(64)] float2
// Coalesced via LDS tile transpose: block = (arr, 16-pair tile).
// Reads: contiguous 256-float2 runs (512 B/wave). Writes: 128 B segments.
__global__ __launch_bounds__(256) void k_wt(const float* __restrict__ fw0,
                                            const float* __restrict__ fw1,
                                            float2* __restrict__ WT) {
    __shared__ float2 Ls[16][257];  // [oo][mx*16+ky], +1 pad -> <=2-way bank alias (free)
    int blk = blockIdx.x;       // 0..511
    int arr = blk >> 8;         // 0: fw0, 1: fw1
    int tile = blk & 255;       // pairs p = tile*16 .. tile*16+15, p = i*64+o
    const float2* s2 = (const float2*)(arr ? fw1 : fw0);
    int t = (int)threadIdx.x;
    // load: iteration k reads row oo=k at q=t (coalesced)
    for (int e = t; e < 4096; e += 256) {
        int oo = e >> 8;        // pair within tile
        int q = e & 255;        // mx*16 + ky
        Ls[oo][q] = s2[(size_t)(tile * 16 + oo) * 256 + q];
    }
    __syncthreads();
    int i = (tile * 16) >> 6;   // 16 | 64 so the 16-pair tile stays in one i-row
    int o0 = (tile * 16) & 63;
    for (int e = t; e < 4096; e += 256) {
        int oo = e & 15;
        int q = e >> 4;
        int mx = q >> 4, ky = q & 15;
        int m = arr * 16 + mx;
        WT[((size_t)(m * 16 + ky) * 64 + i) * 64 + o0 + oo] = Ls[oo][q];
    }
}

// ---------------------------------------------------------------------------
// k_prep: WbT[o][k] = bf16(Wres[k][o]); Tg[y][kk] = bf16(kk&1 ? -sin : cos)
__global__ __launch_bounds__(256) void k_prep(const float* __restrict__ Wres,
                                              unsigned short* __restrict__ WbT,
                                              unsigned short* __restrict__ Tg) {
    int e = blockIdx.x * 256 + (int)threadIdx.x;  // [0, 12288)
    if (e < 4096) {
        int o = e >> 6, k = e & 63;
        WbT[o * 64 + k] = f2b(Wres[k * 64 + o]);
    } else {
        int f = e - 4096;  // [0, 8192)
        int y = f >> 5, kk = f & 31, ky = kk >> 1;
        int p = (ky * y) & 255;
        float ang = (float)p * (float)(2.0 * M_PI / 256.0);
        float s, c;
        sincosf(ang, &s, &c);
        Tg[f] = f2b((kk & 1) ? -s : c);
    }
}

// ---------------------------------------------------------------------------
// k_fwd_y: A[b,x,ky,i] = sum_y X[b,x,y,i] e^{-2pi i ky y/256}
// Block handles 2 x-values; thread = (x2, ky, 8-channel group): 16 FMA per
// table-read+index update (was 8) -> ~20% fewer VALU instrs per result.
__global__ __launch_bounds__(256) void k_fwd_y(const float* __restrict__ X,
                                               float2* __restrict__ A) {
    __shared__ float2 tab[256];
    build_tab(tab);
    __syncthreads();
    int b = blockIdx.x >> 7;
    int xp = blockIdx.x & 127;
    int t = (int)threadIdx.x;
    int x2 = t >> 7;            // 0..1
    int ky = (t >> 3) & 15;     // 0..15
    int ig = t & 7;             // 0..7 (8 channels = 2 float4)
    int x = xp * 2 + x2;
    float ar[8], ai[8];
#pragma unroll
    for (int k = 0; k < 8; k++) { ar[k] = 0.f; ai[k] = 0.f; }
    const float4* Xr = (const float4*)(X + ((size_t)(b * 256 + x)) * 256 * 64);
    int p = 0;
#pragma unroll 4
    for (int y = 0; y < 256; y++) {
        float4 v0 = Xr[y * 16 + ig * 2];
        float4 v1 = Xr[y * 16 + ig * 2 + 1];
        float2 cs = tab[p];
        p = (p + ky) & 255;
        ar[0] += v0.x * cs.x; ai[0] -= v0.x * cs.y;
        ar[1] += v0.y * cs.x; ai[1] -= v0.y * cs.y;
        ar[2] += v0.z * cs.x; ai[2] -= v0.z * cs.y;
        ar[3] += v0.w * cs.x; ai[3] -= v0.w * cs.y;
        ar[4] += v1.x * cs.x; ai[4] -= v1.x * cs.y;
        ar[5] += v1.y * cs.x; ai[5] -= v1.y * cs.y;
        ar[6] += v1.z * cs.x; ai[6] -= v1.z * cs.y;
        ar[7] += v1.w * cs.x; ai[7] -= v1.w * cs.y;
    }
    float4* Aw4 = (float4*)(A + ((size_t)(b * 256 + x)) * 16 * 64 + ky * 64 + ig * 8);
    Aw4[0] = make_float4(ar[0], ai[0], ar[1], ai[1]);
    Aw4[1] = make_float4(ar[2], ai[2], ar[3], ai[3]);
    Aw4[2] = make_float4(ar[4], ai[4], ar[5], ai[5]);
    Aw4[3] = make_float4(ar[6], ai[6], ar[7], ai[7]);
}

// ---------------------------------------------------------------------------
// k_fwd_x: C[b,ky,m,i] = (1/256) sum_x A[b,x,ky,i] e^{-i 2pi kx x/256}
// Incremental phase accumulation (add+and) instead of v_mul_lo per iter.
__global__ __launch_bounds__(256) void k_fwd_x(const float2* __restrict__ A,
                                               float2* __restrict__ C) {
    __shared__ float2 tab[256];
    __shared__ float2 red[4 * 8 * 64];
    int bi = blockIdx.x;
    int b = bi >> 6;
    int ky = (bi >> 2) & 15;
    int mg = bi & 3;
    build_tab(tab);
    __syncthreads();
    int t = (int)threadIdx.x;
    int i = t & 63;
    int xg = t >> 6;
    float cr[8], ci[8];
    int pj[8], st[8];
#pragma unroll
    for (int j = 0; j < 8; j++) {
        cr[j] = 0.f; ci[j] = 0.f;
        int m = mg * 8 + j;
        int kx = (m < 16) ? m : (m + 224);
        pj[j] = (kx * xg) & 255;
        st[j] = (kx * 4) & 255;
    }
    const float2* Ap = A + ((size_t)b * 256) * 16 * 64 + ky * 64 + i;
    for (int x = xg; x < 256; x += 4) {
        float2 a = Ap[(size_t)x * 16 * 64];
#pragma unroll
        for (int j = 0; j < 8; j++) {
            float2 tc = tab[pj[j]];
            pj[j] = (pj[j] + st[j]) & 255;
            cr[j] += a.x * tc.x + a.y * tc.y;
            ci[j] += a.y * tc.x - a.x * tc.y;
        }
    }
#pragma unroll
    for (int j = 0; j < 8; j++) red[(xg * 8 + j) * 64 + i] = make_float2(cr[j], ci[j]);
    __syncthreads();
    const float sc = 1.0f / 256.0f;
    for (int e = t; e < 8 * 64; e += 256) {
        int j = e >> 6;
        int ii = e & 63;
        float2 s = red[j * 64 + ii];
        float2 s1 = red[(8 + j) * 64 + ii];
        float2 s2 = red[(16 + j) * 64 + ii];
        float2 s3 = red[(24 + j) * 64 + ii];
        float rr = (s.x + s1.x) + (s2.x + s3.x);
        float im = (s.y + s1.y) + (s2.y + s3.y);
        int m = mg * 8 + j;
        C[(((size_t)b * 16 + ky) * 32 + m) * 64 + ii] = make_float2(rr * sc, im * sc);
    }
}

// ---------------------------------------------------------------------------
// k_mix: D[b,ky,m,o] = sum_i C[b,ky,m,i] * w[i,o] (complex)
__global__ __launch_bounds__(256) void k_mix(const float2* __restrict__ C,
                                             const float2* __restrict__ WT,
                                             float2* __restrict__ D) {
    __shared__ float2 Ws[64 * 64];
    __shared__ float2 Cs[8 * 64];
    __shared__ float2 red[4 * 8 * 64];
    int bi = blockIdx.x;
    int ky = bi >> 5;
    int m = bi & 31;
    int t = (int)threadIdx.x;
    const float4* Wsrc = (const float4*)(WT + ((size_t)(m * 16 + ky)) * 4096);
    float4* Wd = (float4*)Ws;
    for (int e = t; e < 2048; e += 256) Wd[e] = Wsrc[e];
    for (int e = t; e < 512; e += 256) {
        int b = e >> 6;
        int i = e & 63;
        Cs[e] = C[(((size_t)b * 16 + ky) * 32 + m) * 64 + i];
    }
    __syncthreads();
    int o = t & 63;
    int ig = t >> 6;
    float dr[8], di[8];
#pragma unroll
    for (int b = 0; b < 8; b++) { dr[b] = 0.f; di[b] = 0.f; }
    for (int i2 = ig * 16; i2 < ig * 16 + 16; i2++) {
        float2 w = Ws[i2 * 64 + o];
#pragma unroll
        for (int b = 0; b < 8; b++) {
            float2 c = Cs[b * 64 + i2];
            dr[b] += c.x * w.x - c.y * w.y;
            di[b] += c.x * w.y + c.y * w.x;
        }
    }
#pragma unroll
    for (int b = 0; b < 8; b++) red[(ig * 8 + b) * 64 + o] = make_float2(dr[b], di[b]);
    __syncthreads();
    for (int e = t; e < 512; e += 256) {
        int b = e >> 6;
        int oo = e & 63;
        float2 s = red[b * 64 + oo];
        float2 s1 = red[(8 + b) * 64 + oo];
        float2 s2 = red[(16 + b) * 64 + oo];
        float2 s3 = red[(24 + b) * 64 + oo];
        D[(((size_t)b * 16 + ky) * 32 + m) * 64 + oo] =
            make_float2((s.x + s1.x) + (s2.x + s3.x), (s.y + s1.y) + (s2.y + s3.y));
    }
}

// ---------------------------------------------------------------------------
// k_inv_x: G[b,x,ky,o] = sum_m D[b,ky,m,o] e^{+i 2pi kx x/256}
// Incremental phase over m (statically-unrolled jump at m==15).
__global__ __launch_bounds__(256) void k_inv_x(const float2* __restrict__ D,
                                               float2* __restrict__ G) {
    __shared__ float2 tab[256];
    __shared__ float2 Ds[32 * 64];
    int bi = blockIdx.x;
    int b = bi >> 7;
    int ky = (bi >> 3) & 15;
    int xc = bi & 7;
    build_tab(tab);
    int t = (int)threadIdx.x;
    const float4* Dsrc = (const float4*)(D + (((size_t)b * 16 + ky) * 32) * 64);
    float4* Dd = (float4*)Ds;
    for (int e = t; e < 1024; e += 256) Dd[e] = Dsrc[e];
    __syncthreads();
    int o = t & 63;
    int xg = t >> 6;
#pragma unroll
    for (int j = 0; j < 8; j++) {
        int x = xc * 32 + xg * 8 + j;
        int ex = (224 * x) & 255;   // phase jump kx: 15 -> 240
        float gr = 0.f, gi = 0.f;
        int p = 0;
#pragma unroll
        for (int m = 0; m < 32; m++) {
            float2 tc = tab[p];
            p = (p + x) & 255;
            if (m == 15) p = (p + ex) & 255;
            float2 d = Ds[m * 64 + o];
            gr += d.x * tc.x - d.y * tc.y;
            gi += d.x * tc.y + d.y * tc.x;
        }
        G[((size_t)(b * 256 + x) * 16 + ky) * 64 + o] = make_float2(gr, gi);
    }
}

// ---------------------------------------------------------------------------
// k_out: MFMA GEMM, K=96: out[y][o] = silu(X[y][:]Wres + T[y][:]Gfold + b)
// Block = (b,x). 4 waves; wave w owns y in [64w, 64w+64). A from global, B
// (Wres^T bf16, Gfold LDS). D-layout: row=(lane>>4)*4+reg, col=lane&15.
__global__ __launch_bounds__(256) void k_out(const float* __restrict__ X,
                                             const float2* __restrict__ G,
                                             const unsigned short* __restrict__ WbT,
                                             const unsigned short* __restrict__ Tg,
                                             const float* __restrict__ bres,
                                             float* __restrict__ out) {
    __shared__ unsigned short Bsp[64 * 32];  // Gfold^T: [o][kk]
    int b = blockIdx.x >> 8;
    int x = blockIdx.x & 255;
    int t = (int)threadIdx.x;

    // fold G row -> Bspec[kk][o] (stored transposed [o][kk]) with irfft scale
    const float2* Gp = G + ((size_t)(b * 256 + x)) * 16 * 64;
    for (int e = t; e < 1024; e += 256) {
        int ky = e >> 6, o = e & 63;
        float2 g = Gp[e];
        float sc = (ky == 0) ? (1.0f / 256.0f) : (2.0f / 256.0f);
        Bsp[o * 32 + 2 * ky]     = f2b(g.x * sc);
        Bsp[o * 32 + 2 * ky + 1] = f2b(g.y * sc);
    }
    __syncthreads();

    int w = t >> 6;
    int l = t & 63;
    int m16 = l & 15;
    int quad = l >> 4;

    // B-fragments: B[k][n], k = quad*8+j, n = 16*nt + m16
    short8 bw0[4], bw1[4], bs[4];
    float br[4];
#pragma unroll
    for (int nt = 0; nt < 4; nt++) {
        int o = nt * 16 + m16;
        bw0[nt] = *(const short8*)(WbT + o * 64 + quad * 8);
        bw1[nt] = *(const short8*)(WbT + o * 64 + 32 + quad * 8);
        bs[nt]  = *(const short8*)(Bsp + o * 32 + quad * 8);
        br[nt]  = bres[o];
    }

    const float* Xrow = X + ((size_t)(b * 256 + x)) * 256 * 64;
    float* orow = out + ((size_t)(b * 256 + x)) * 256 * 64;

    f32x4 acc[4][4];
#pragma unroll
    for (int mt = 0; mt < 4; mt++)
#pragma unroll
        for (int nt = 0; nt < 4; nt++) acc[mt][nt] = (f32x4){0.f, 0.f, 0.f, 0.f};

#pragma unroll
    for (int mt = 0; mt < 4; mt++) {
        int y = w * 64 + mt * 16 + m16;  // A-frag m index
        // A-frags from global: X (f32->bf16), T (bf16)
        const float4* xp = (const float4*)(Xrow + (size_t)y * 64 + quad * 8);
        float4 v0 = xp[0], v1 = xp[1];
        const float4* xq = (const float4*)(Xrow + (size_t)y * 64 + 32 + quad * 8);
        float4 v2 = xq[0], v3 = xq[1];
        short8 a0, a1;
        a0[0] = (short)f2b(v0.x); a0[1] = (short)f2b(v0.y);
        a0[2] = (short)f2b(v0.z); a0[3] = (short)f2b(v0.w);
        a0[4] = (short)f2b(v1.x); a0[5] = (short)f2b(v1.y);
        a0[6] = (short)f2b(v1.z); a0[7] = (short)f2b(v1.w);
        a1[0] = (short)f2b(v2.x); a1[1] = (short)f2b(v2.y);
        a1[2] = (short)f2b(v2.z); a1[3] = (short)f2b(v2.w);
        a1[4] = (short)f2b(v3.x); a1[5] = (short)f2b(v3.y);
        a1[6] = (short)f2b(v3.z); a1[7] = (short)f2b(v3.w);
        short8 aT = *(const short8*)(Tg + (size_t)y * 32 + quad * 8);
#pragma unroll
        for (int nt = 0; nt < 4; nt++) {
            acc[mt][nt] = __builtin_amdgcn_mfma_f32_16x16x32_bf16(a0, bw0[nt], acc[mt][nt], 0, 0, 0);
            acc[mt][nt] = __builtin_amdgcn_mfma_f32_16x16x32_bf16(a1, bw1[nt], acc[mt][nt], 0, 0, 0);
            acc[mt][nt] = __builtin_amdgcn_mfma_f32_16x16x32_bf16(aT, bs[nt],  acc[mt][nt], 0, 0, 0);
        }
    }

    // epilogue: bias + SiLU (rcp approx: rel err ~2^-22, far below bf16 path noise)
#pragma unroll
    for (int mt = 0; mt < 4; mt++) {
#pragma unroll
        for (int nt = 0; nt < 4; nt++) {
            int o = nt * 16 + m16;
#pragma unroll
            for (int r = 0; r < 4; r++) {
                int y = w * 64 + mt * 16 + quad * 4 + r;
                float v = acc[mt][nt][r] + br[nt];
                float sg = __builtin_amdgcn_rcpf(1.0f + __expf(-v));
                orow[(size_t)y * 64 + o] = v * sg;
            }
        }
    }
}

extern "C" void kernel_launch(void* const* d_in, const int* in_sizes, int n_in,
                              void* d_out, int out_size, void* d_ws, size_t ws_size,
                              hipStream_t stream) {
    const float* X    = (const float*)d_in[0];
    const float* Wres = (const float*)d_in[1];
    const float* bres = (const float*)d_in[2];
    const float* fw0  = (const float*)d_in[3];
    const float* fw1  = (const float*)d_in[4];
    float* out = (float*)d_out;

    // workspace (float2 units): A/G 2097152 | C 262144 | D 262144 | WT 2097152
    float2* A  = (float2*)d_ws;
    float2* C  = A + 2097152;
    float2* D  = C + 262144;
    float2* WT = D + 262144;
    float2* G  = A;  // reuse A after k_fwd_x consumes it
    // WbT/Tg overlay the C region (free after k_mix): 4096 + 8192 ushorts = 24 KB
    unsigned short* WbT = (unsigned short*)C;
    unsigned short* Tg  = WbT + 4096;

    k_wt<<<512, 256, 0, stream>>>(fw0, fw1, WT);
    k_fwd_y<<<NB * 128, 256, 0, stream>>>(X, A);
    k_fwd_x<<<NB * 16 * 4, 256, 0, stream>>>(A, C);
    k_mix<<<16 * 32, 256, 0, stream>>>(C, WT, D);
    k_prep<<<48, 256, 0, stream>>>(Wres, WbT, Tg);   // after k_mix (reuses C region)
    k_inv_x<<<NB * 16 * 8, 256, 0, stream>>>(D, G);
    k_out<<<NB * 256, 256, 0, stream>>>(X, G, WbT, Tg, bres, out);
}

// Round 2
// 371.784 us; speedup vs baseline: 1.2692x; 1.2692x over previous
//
#include <hip/hip_runtime.h>
#include <math.h>

#define RDIM 256
#define CIN 64
#define COUT 64
#define MODES 16
#define NB 8

typedef short short8 __attribute__((ext_vector_type(8)));
typedef float f32x4 __attribute__((ext_vector_type(4)));

// f32 -> bf16 bits, round-to-nearest-even
__device__ __forceinline__ unsigned short f2b(float f) {
    unsigned u = __builtin_bit_cast(unsigned, f);
    unsigned r = (u + 0x7FFFu + ((u >> 16) & 1u)) >> 16;
    return (unsigned short)r;
}

// cos/sin table: tab[p] = (cos(2*pi*p/256), sin(2*pi*p/256))
__device__ __forceinline__ void build_tab(float2* tab) {
    for (int p = (int)threadIdx.x; p < 256; p += (int)blockDim.x) {
        float ang = (float)p * (float)(2.0 * M_PI / 256.0);
        float s, c;
        sincosf(ang, &s, &c);
        tab[p] = make_float2(c, s);
    }
}

// ---------------------------------------------------------------------------
// k_tf: forward-DFT twiddle matrix for MFMA: Tf[kyc(32)][y(256)] bf16
//   Tf[2*ky+0][y] =  cos(2*pi*ky*y/256)
//   Tf[2*ky+1][y] = -sin(2*pi*ky*y/256)
__global__ __launch_bounds__(256) void k_tf(unsigned short* __restrict__ Tf) {
    int e = blockIdx.x * 256 + (int)threadIdx.x;  // [0, 8192)
    int kyc = e >> 8, y = e & 255, ky = kyc >> 1;
    int p = (ky * y) & 255;
    float ang = (float)p * (float)(2.0 * M_PI / 256.0);
    float s, c;
    sincosf(ang, &s, &c);
    Tf[e] = f2b((kyc & 1) ? -s : c);
}

// ---------------------------------------------------------------------------
// k_wt: transpose weights fw0/fw1 [i,o,mx,ky,2] -> WT[m(32)][ky(16)][i(64)][o(64)] float2
__global__ __launch_bounds__(256) void k_wt(const float* __restrict__ fw0,
                                            const float* __restrict__ fw1,
                                            float2* __restrict__ WT) {
    __shared__ float2 Ls[16][257];  // [oo][mx*16+ky], +1 pad
    int blk = blockIdx.x;       // 0..511
    int arr = blk >> 8;         // 0: fw0, 1: fw1
    int tile = blk & 255;       // pairs p = tile*16 .. tile*16+15, p = i*64+o
    const float2* s2 = (const float2*)(arr ? fw1 : fw0);
    int t = (int)threadIdx.x;
    for (int e = t; e < 4096; e += 256) {
        int oo = e >> 8;
        int q = e & 255;
        Ls[oo][q] = s2[(size_t)(tile * 16 + oo) * 256 + q];
    }
    __syncthreads();
    int i = (tile * 16) >> 6;
    int o0 = (tile * 16) & 63;
    for (int e = t; e < 4096; e += 256) {
        int oo = e & 15;
        int q = e >> 4;
        int mx = q >> 4, ky = q & 15;
        int m = arr * 16 + mx;
        WT[((size_t)(m * 16 + ky) * 64 + i) * 64 + o0 + oo] = Ls[oo][q];
    }
}

// ---------------------------------------------------------------------------
// k_prep: WbT[o][k] = bf16(Wres[k][o]); Tg[y][kk] = bf16(kk&1 ? -sin : cos)
__global__ __launch_bounds__(256) void k_prep(const float* __restrict__ Wres,
                                              unsigned short* __restrict__ WbT,
                                              unsigned short* __restrict__ Tg) {
    int e = blockIdx.x * 256 + (int)threadIdx.x;  // [0, 12288)
    if (e < 4096) {
        int o = e >> 6, k = e & 63;
        WbT[o * 64 + k] = f2b(Wres[k * 64 + o]);
    } else {
        int f = e - 4096;  // [0, 8192)
        int y = f >> 5, kk = f & 31, ky = kk >> 1;
        int p = (ky * y) & 255;
        float ang = (float)p * (float)(2.0 * M_PI / 256.0);
        float s, c;
        sincosf(ang, &s, &c);
        Tg[f] = f2b((kk & 1) ? -s : c);
    }
}

// ---------------------------------------------------------------------------
// k_fwd_y (MFMA): A[b,x,ky,i] = sum_y X[b,x,y,i] e^{-2pi i ky y/256}
// Block = (b,x). Phase 1: coalesced read of the 64KB X row, f2b, transpose
// into LDS Xb[i][y] bf16 with XOR swizzle col^=(i&7) (conflict-free both
// sides). Phase 2: D[kyc(32)][i(64)] = Tf(32x256) @ Xb(256x64) via 16x16x32
// bf16 MFMA; wave w owns i-tile w*16. A-frags from global Tf (16KB, L2-hot).
__global__ __launch_bounds__(256) void k_fwd_y(const float* __restrict__ X,
                                               const unsigned short* __restrict__ Tf,
                                               float2* __restrict__ A) {
    __shared__ short8 Xb[64 * 32];  // [i][y8 (16B units)], col swizzled
    int b = blockIdx.x >> 8;
    int x = blockIdx.x & 255;
    int t = (int)threadIdx.x;
    int w = t >> 6;
    int l = t & 63;

    // ---- phase 1: stage + transpose-convert ----
    const float* Xr = X + ((size_t)(b * 256 + x)) * 256 * 64;
#pragma unroll
    for (int s = 0; s < 8; s++) {
        int y8 = w * 8 + s;                 // 8 consecutive y rows start at y8*8
        const float* base = Xr + (size_t)y8 * 512 + l;
        short8 hb;
#pragma unroll
        for (int j = 0; j < 8; j++) hb[j] = (short)f2b(base[j * 64]);
        Xb[l * 32 + (y8 ^ (l & 7))] = hb;
    }
    __syncthreads();

    // ---- phase 2: MFMA ----
    int m16 = l & 15;
    int quad = l >> 4;
    int iRow = w * 16 + m16;                // output i (also B-frag n)
    int isw = iRow & 7;

    f32x4 acc0 = (f32x4){0.f, 0.f, 0.f, 0.f};
    f32x4 acc1 = (f32x4){0.f, 0.f, 0.f, 0.f};
    const unsigned short* T0 = Tf + (size_t)m16 * 256 + quad * 8;
#pragma unroll
    for (int ks = 0; ks < 8; ks++) {
        short8 a0 = *(const short8*)(T0 + ks * 32);
        short8 a1 = *(const short8*)(T0 + 4096 + ks * 32);  // mt=1: +16 rows
        int y8r = ks * 4 + quad;
        short8 bfrag = Xb[iRow * 32 + (y8r ^ isw)];
        acc0 = __builtin_amdgcn_mfma_f32_16x16x32_bf16(a0, bfrag, acc0, 0, 0, 0);
        acc1 = __builtin_amdgcn_mfma_f32_16x16x32_bf16(a1, bfrag, acc1, 0, 0, 0);
    }

    // ---- epilogue: D row kyc = mt*16 + quad*4 + r; pairs (r,r+1) = (re,im) ----
    float2* Aout = A + ((size_t)(b * 256 + x)) * 16 * 64;
    int ky0 = (quad * 4) >> 1;              // mt=0: kyc 0..15
    Aout[(size_t)ky0 * 64 + iRow] = make_float2(acc0[0], acc0[1]);
    Aout[(size_t)(ky0 + 1) * 64 + iRow] = make_float2(acc0[2], acc0[3]);
    int ky1 = (16 + quad * 4) >> 1;         // mt=1: kyc 16..31
    Aout[(size_t)ky1 * 64 + iRow] = make_float2(acc1[0], acc1[1]);
    Aout[(size_t)(ky1 + 1) * 64 + iRow] = make_float2(acc1[2], acc1[3]);
}

// ---------------------------------------------------------------------------
// k_fwd_x: C[b,ky,m,i] = (1/256) sum_x A[b,x,ky,i] e^{-i 2pi kx x/256}
__global__ __launch_bounds__(256) void k_fwd_x(const float2* __restrict__ A,
                                               float2* __restrict__ C) {
    __shared__ float2 tab[256];
    __shared__ float2 red[4 * 8 * 64];
    int bi = blockIdx.x;
    int b = bi >> 6;
    int ky = (bi >> 2) & 15;
    int mg = bi & 3;
    build_tab(tab);
    __syncthreads();
    int t = (int)threadIdx.x;
    int i = t & 63;
    int xg = t >> 6;
    float cr[8], ci[8];
    int pj[8], st[8];
#pragma unroll
    for (int j = 0; j < 8; j++) {
        cr[j] = 0.f; ci[j] = 0.f;
        int m = mg * 8 + j;
        int kx = (m < 16) ? m : (m + 224);
        pj[j] = (kx * xg) & 255;
        st[j] = (kx * 4) & 255;
    }
    const float2* Ap = A + ((size_t)b * 256) * 16 * 64 + ky * 64 + i;
    for (int x = xg; x < 256; x += 4) {
        float2 a = Ap[(size_t)x * 16 * 64];
#pragma unroll
        for (int j = 0; j < 8; j++) {
            float2 tc = tab[pj[j]];
            pj[j] = (pj[j] + st[j]) & 255;
            cr[j] += a.x * tc.x + a.y * tc.y;
            ci[j] += a.y * tc.x - a.x * tc.y;
        }
    }
#pragma unroll
    for (int j = 0; j < 8; j++) red[(xg * 8 + j) * 64 + i] = make_float2(cr[j], ci[j]);
    __syncthreads();
    const float sc = 1.0f / 256.0f;
    for (int e = t; e < 8 * 64; e += 256) {
        int j = e >> 6;
        int ii = e & 63;
        float2 s = red[j * 64 + ii];
        float2 s1 = red[(8 + j) * 64 + ii];
        float2 s2 = red[(16 + j) * 64 + ii];
        float2 s3 = red[(24 + j) * 64 + ii];
        float rr = (s.x + s1.x) + (s2.x + s3.x);
        float im = (s.y + s1.y) + (s2.y + s3.y);
        int m = mg * 8 + j;
        C[(((size_t)b * 16 + ky) * 32 + m) * 64 + ii] = make_float2(rr * sc, im * sc);
    }
}

// ---------------------------------------------------------------------------
// k_mix: D[b,ky,m,o] = sum_i C[b,ky,m,i] * w[i,o] (complex)
__global__ __launch_bounds__(256) void k_mix(const float2* __restrict__ C,
                                             const float2* __restrict__ WT,
                                             float2* __restrict__ D) {
    __shared__ float2 Ws[64 * 64];
    __shared__ float2 Cs[8 * 64];
    __shared__ float2 red[4 * 8 * 64];
    int bi = blockIdx.x;
    int ky = bi >> 5;
    int m = bi & 31;
    int t = (int)threadIdx.x;
    const float4* Wsrc = (const float4*)(WT + ((size_t)(m * 16 + ky)) * 4096);
    float4* Wd = (float4*)Ws;
    for (int e = t; e < 2048; e += 256) Wd[e] = Wsrc[e];
    for (int e = t; e < 512; e += 256) {
        int b = e >> 6;
        int i = e & 63;
        Cs[e] = C[(((size_t)b * 16 + ky) * 32 + m) * 64 + i];
    }
    __syncthreads();
    int o = t & 63;
    int ig = t >> 6;
    float dr[8], di[8];
#pragma unroll
    for (int b = 0; b < 8; b++) { dr[b] = 0.f; di[b] = 0.f; }
    for (int i2 = ig * 16; i2 < ig * 16 + 16; i2++) {
        float2 w = Ws[i2 * 64 + o];
#pragma unroll
        for (int b = 0; b < 8; b++) {
            float2 c = Cs[b * 64 + i2];
            dr[b] += c.x * w.x - c.y * w.y;
            di[b] += c.x * w.y + c.y * w.x;
        }
    }
#pragma unroll
    for (int b = 0; b < 8; b++) red[(ig * 8 + b) * 64 + o] = make_float2(dr[b], di[b]);
    __syncthreads();
    for (int e = t; e < 512; e += 256) {
        int b = e >> 6;
        int oo = e & 63;
        float2 s = red[b * 64 + oo];
        float2 s1 = red[(8 + b) * 64 + oo];
        float2 s2 = red[(16 + b) * 64 + oo];
        float2 s3 = red[(24 + b) * 64 + oo];
        D[(((size_t)b * 16 + ky) * 32 + m) * 64 + oo] =
            make_float2((s.x + s1.x) + (s2.x + s3.x), (s.y + s1.y) + (s2.y + s3.y));
    }
}

// ---------------------------------------------------------------------------
// k_inv_x: G[b,x,ky,o] = sum_m D[b,ky,m,o] e^{+i 2pi kx x/256}
__global__ __launch_bounds__(256) void k_inv_x(const float2* __restrict__ D,
                                               float2* __restrict__ G) {
    __shared__ float2 tab[256];
    __shared__ float2 Ds[32 * 64];
    int bi = blockIdx.x;
    int b = bi >> 7;
    int ky = (bi >> 3) & 15;
    int xc = bi & 7;
    build_tab(tab);
    int t = (int)threadIdx.x;
    const float4* Dsrc = (const float4*)(D + (((size_t)b * 16 + ky) * 32) * 64);
    float4* Dd = (float4*)Ds;
    for (int e = t; e < 1024; e += 256) Dd[e] = Dsrc[e];
    __syncthreads();
    int o = t & 63;
    int xg = t >> 6;
#pragma unroll
    for (int j = 0; j < 8; j++) {
        int x = xc * 32 + xg * 8 + j;
        int ex = (224 * x) & 255;   // phase jump kx: 15 -> 240
        float gr = 0.f, gi = 0.f;
        int p = 0;
#pragma unroll
        for (int m = 0; m < 32; m++) {
            float2 tc = tab[p];
            p = (p + x) & 255;
            if (m == 15) p = (p + ex) & 255;
            float2 d = Ds[m * 64 + o];
            gr += d.x * tc.x - d.y * tc.y;
            gi += d.x * tc.y + d.y * tc.x;
        }
        G[((size_t)(b * 256 + x) * 16 + ky) * 64 + o] = make_float2(gr, gi);
    }
}

// ---------------------------------------------------------------------------
// k_out: MFMA GEMM, K=96: out[y][o] = silu(X[y][:]Wres + T[y][:]Gfold + b)
__global__ __launch_bounds__(256) void k_out(const float* __restrict__ X,
                                             const float2* __restrict__ G,
                                             const unsigned short* __restrict__ WbT,
                                             const unsigned short* __restrict__ Tg,
                                             const float* __restrict__ bres,
                                             float* __restrict__ out) {
    __shared__ unsigned short Bsp[64 * 32];  // Gfold^T: [o][kk]
    int b = blockIdx.x >> 8;
    int x = blockIdx.x & 255;
    int t = (int)threadIdx.x;

    const float2* Gp = G + ((size_t)(b * 256 + x)) * 16 * 64;
    for (int e = t; e < 1024; e += 256) {
        int ky = e >> 6, o = e & 63;
        float2 g = Gp[e];
        float sc = (ky == 0) ? (1.0f / 256.0f) : (2.0f / 256.0f);
        Bsp[o * 32 + 2 * ky]     = f2b(g.x * sc);
        Bsp[o * 32 + 2 * ky + 1] = f2b(g.y * sc);
    }
    __syncthreads();

    int w = t >> 6;
    int l = t & 63;
    int m16 = l & 15;
    int quad = l >> 4;

    short8 bw0[4], bw1[4], bs[4];
    float br[4];
#pragma unroll
    for (int nt = 0; nt < 4; nt++) {
        int o = nt * 16 + m16;
        bw0[nt] = *(const short8*)(WbT + o * 64 + quad * 8);
        bw1[nt] = *(const short8*)(WbT + o * 64 + 32 + quad * 8);
        bs[nt]  = *(const short8*)(Bsp + o * 32 + quad * 8);
        br[nt]  = bres[o];
    }

    const float* Xrow = X + ((size_t)(b * 256 + x)) * 256 * 64;
    float* orow = out + ((size_t)(b * 256 + x)) * 256 * 64;

    f32x4 acc[4][4];
#pragma unroll
    for (int mt = 0; mt < 4; mt++)
#pragma unroll
        for (int nt = 0; nt < 4; nt++) acc[mt][nt] = (f32x4){0.f, 0.f, 0.f, 0.f};

#pragma unroll
    for (int mt = 0; mt < 4; mt++) {
        int y = w * 64 + mt * 16 + m16;
        const float4* xp = (const float4*)(Xrow + (size_t)y * 64 + quad * 8);
        float4 v0 = xp[0], v1 = xp[1];
        const float4* xq = (const float4*)(Xrow + (size_t)y * 64 + 32 + quad * 8);
        float4 v2 = xq[0], v3 = xq[1];
        short8 a0, a1;
        a0[0] = (short)f2b(v0.x); a0[1] = (short)f2b(v0.y);
        a0[2] = (short)f2b(v0.z); a0[3] = (short)f2b(v0.w);
        a0[4] = (short)f2b(v1.x); a0[5] = (short)f2b(v1.y);
        a0[6] = (short)f2b(v1.z); a0[7] = (short)f2b(v1.w);
        a1[0] = (short)f2b(v2.x); a1[1] = (short)f2b(v2.y);
        a1[2] = (short)f2b(v2.z); a1[3] = (short)f2b(v2.w);
        a1[4] = (short)f2b(v3.x); a1[5] = (short)f2b(v3.y);
        a1[6] = (short)f2b(v3.z); a1[7] = (short)f2b(v3.w);
        short8 aT = *(const short8*)(Tg + (size_t)y * 32 + quad * 8);
#pragma unroll
        for (int nt = 0; nt < 4; nt++) {
            acc[mt][nt] = __builtin_amdgcn_mfma_f32_16x16x32_bf16(a0, bw0[nt], acc[mt][nt], 0, 0, 0);
            acc[mt][nt] = __builtin_amdgcn_mfma_f32_16x16x32_bf16(a1, bw1[nt], acc[mt][nt], 0, 0, 0);
            acc[mt][nt] = __builtin_amdgcn_mfma_f32_16x16x32_bf16(aT, bs[nt],  acc[mt][nt], 0, 0, 0);
        }
    }

#pragma unroll
    for (int mt = 0; mt < 4; mt++) {
#pragma unroll
        for (int nt = 0; nt < 4; nt++) {
            int o = nt * 16 + m16;
#pragma unroll
            for (int r = 0; r < 4; r++) {
                int y = w * 64 + mt * 16 + quad * 4 + r;
                float v = acc[mt][nt][r] + br[nt];
                float sg = __builtin_amdgcn_rcpf(1.0f + __expf(-v));
                orow[(size_t)y * 64 + o] = v * sg;
            }
        }
    }
}

extern "C" void kernel_launch(void* const* d_in, const int* in_sizes, int n_in,
                              void* d_out, int out_size, void* d_ws, size_t ws_size,
                              hipStream_t stream) {
    const float* X    = (const float*)d_in[0];
    const float* Wres = (const float*)d_in[1];
    const float* bres = (const float*)d_in[2];
    const float* fw0  = (const float*)d_in[3];
    const float* fw1  = (const float*)d_in[4];
    float* out = (float*)d_out;

    // workspace (float2 units): A/G 2097152 | C 262144 | D 262144 | WT 2097152
    float2* A  = (float2*)d_ws;
    float2* C  = A + 2097152;
    float2* D  = C + 262144;
    float2* WT = D + 262144;
    float2* G  = A;  // reuse A after k_fwd_x consumes it
    // WbT/Tg overlay the C region (free after k_mix): 4096 + 8192 ushorts = 24 KB
    unsigned short* WbT = (unsigned short*)C;
    unsigned short* Tg  = WbT + 4096;
    // Tf (forward twiddles, 16 KB) overlays the D region (free until k_mix)
    unsigned short* Tf  = (unsigned short*)D;

    k_wt<<<512, 256, 0, stream>>>(fw0, fw1, WT);
    k_tf<<<32, 256, 0, stream>>>(Tf);
    k_fwd_y<<<NB * 256, 256, 0, stream>>>(X, Tf, A);
    k_fwd_x<<<NB * 16 * 4, 256, 0, stream>>>(A, C);
    k_mix<<<16 * 32, 256, 0, stream>>>(C, WT, D);
    k_prep<<<48, 256, 0, stream>>>(Wres, WbT, Tg);   // after k_mix (reuses C region)
    k_inv_x<<<NB * 16 * 8, 256, 0, stream>>>(D, G);
    k_out<<<NB * 256, 256, 0, stream>>>(X, G, WbT, Tg, bres, out);
}

// Round 3
// 324.564 us; speedup vs baseline: 1.4539x; 1.1455x over previous
//
#include <hip/hip_runtime.h>
#include <math.h>

#define RDIM 256
#define CIN 64
#define COUT 64
#define MODES 16
#define NB 8

typedef short short8 __attribute__((ext_vector_type(8)));
typedef float f32x4 __attribute__((ext_vector_type(4)));

// f32 -> bf16 bits, round-to-nearest-even
__device__ __forceinline__ unsigned short f2b(float f) {
    unsigned u = __builtin_bit_cast(unsigned, f);
    unsigned r = (u + 0x7FFFu + ((u >> 16) & 1u)) >> 16;
    return (unsigned short)r;
}

// ---------------------------------------------------------------------------
// k_tf: twiddle tables for the MFMA DFTs.
//  Tf2[kyc(32)][k(256)]: forward-y. k-perm: S=k>>3,j=k&7; w=S>>3,h=(S>>2)&1,
//    q=S&3; y = w*64 + q + 4*(h*8+j). row 2ky=cos, 2ky+1=-sin (theta=2pi ky y/256).
//  T2[r(64)][k(512)]: forward-x, scale 1/256 folded. k-perm: S=k>>3,j=k&7;
//    w=S>>4,bp=(S>>3)&1,a=S&7; d=j>>1,c=j&1; x=w*64+bp+8a+2d. c: 0=Ar,1=Ai.
//    r=2m+cc: cc=0 (C_re): c0->cos, c1->sin; cc=1 (C_im): c0->-sin, c1->cos.
__global__ __launch_bounds__(256) void k_tf(unsigned short* __restrict__ Tf2,
                                            unsigned short* __restrict__ T2) {
    int e = blockIdx.x * 256 + (int)threadIdx.x;  // [0, 40960)
    if (e < 8192) {
        int kyc = e >> 8, k = e & 255;
        int S = k >> 3, j = k & 7;
        int w = S >> 3, h = (S >> 2) & 1, q = S & 3;
        int y = w * 64 + q + 4 * (h * 8 + j);
        int ky = kyc >> 1;
        int p = (ky * y) & 255;
        float ang = (float)p * (float)(2.0 * M_PI / 256.0);
        float sz, cz;
        sincosf(ang, &sz, &cz);
        Tf2[e] = f2b((kyc & 1) ? -sz : cz);
    } else {
        int f = e - 8192;  // [0, 32768)
        int r = f >> 9, k = f & 511;
        int S = k >> 3, j = k & 7;
        int w = S >> 4, bp = (S >> 3) & 1, a = S & 7;
        int d = j >> 1, c = j & 1;
        int x = w * 64 + bp + 8 * a + 2 * d;
        int m = r >> 1, cc = r & 1;
        int kx = (m < 16) ? m : (m + 224);
        int p = (kx * x) & 255;
        float ang = (float)p * (float)(2.0 * M_PI / 256.0);
        float sz, cz;
        sincosf(ang, &sz, &cz);
        float val = (cc == 0) ? (c ? sz : cz) : (c ? cz : -sz);
        T2[f] = f2b(val * (1.0f / 256.0f));
    }
}

// ---------------------------------------------------------------------------
// k_wt: transpose weights fw0/fw1 [i,o,mx,ky,2] -> WT[m(32)][ky(16)][i(64)][o(64)] float2
__global__ __launch_bounds__(256) void k_wt(const float* __restrict__ fw0,
                                            const float* __restrict__ fw1,
                                            float2* __restrict__ WT) {
    __shared__ float2 Ls[16][257];
    int blk = blockIdx.x;       // 0..511
    int arr = blk >> 8;
    int tile = blk & 255;
    const float2* s2 = (const float2*)(arr ? fw1 : fw0);
    int t = (int)threadIdx.x;
    for (int e = t; e < 4096; e += 256) {
        int oo = e >> 8;
        int q = e & 255;
        Ls[oo][q] = s2[(size_t)(tile * 16 + oo) * 256 + q];
    }
    __syncthreads();
    int i = (tile * 16) >> 6;
    int o0 = (tile * 16) & 63;
    for (int e = t; e < 4096; e += 256) {
        int oo = e & 15;
        int q = e >> 4;
        int mx = q >> 4, ky = q & 15;
        int m = arr * 16 + mx;
        WT[((size_t)(m * 16 + ky) * 64 + i) * 64 + o0 + oo] = Ls[oo][q];
    }
}

// ---------------------------------------------------------------------------
// k_prep: WbT[o][k] = bf16(Wres[k][o]); Tg[y][kk]; A2[comp(2)][x(256)][k(64)]
// inverse-x twiddles: k=2m+c; comp0 (G_re): c0->cos, c1->-sin;
// comp1 (G_im): c0->sin, c1->cos.  theta = +2pi kx x/256.
__global__ __launch_bounds__(256) void k_prep(const float* __restrict__ Wres,
                                              unsigned short* __restrict__ WbT,
                                              unsigned short* __restrict__ Tg,
                                              unsigned short* __restrict__ A2) {
    int e = blockIdx.x * 256 + (int)threadIdx.x;  // [0, 45056)
    if (e < 4096) {
        int o = e >> 6, k = e & 63;
        WbT[o * 64 + k] = f2b(Wres[k * 64 + o]);
    } else if (e < 12288) {
        int f = e - 4096;  // [0, 8192)
        int y = f >> 5, kk = f & 31, ky = kk >> 1;
        int p = (ky * y) & 255;
        float ang = (float)p * (float)(2.0 * M_PI / 256.0);
        float sz, cz;
        sincosf(ang, &sz, &cz);
        Tg[f] = f2b((kk & 1) ? -sz : cz);
    } else {
        int f = e - 12288;  // [0, 32768)
        int comp = f >> 14, g = f & 16383;
        int x = g >> 6, k = g & 63;
        int m = k >> 1, c = k & 1;
        int kx = (m < 16) ? m : (m + 224);
        int p = (kx * x) & 255;
        float ang = (float)p * (float)(2.0 * M_PI / 256.0);
        float sz, cz;
        sincosf(ang, &sz, &cz);
        float val = (comp == 0) ? (c ? -sz : cz) : (c ? cz : sz);
        A2[f] = f2b(val);
    }
}

// ---------------------------------------------------------------------------
// k_fwd_y (MFMA): A[b][ky][x][i] = sum_y X[b,x,y,i] e^{-2pi i ky y/256}
// Phase 1: 16 float4 loads/thread (1KB/instr), pack to bf16, LDS Xb[i][slot]
// with slot' = slot ^ (i&7). y-permutation baked into Tf2.
__global__ __launch_bounds__(256) void k_fwd_y(const float* __restrict__ X,
                                               const unsigned short* __restrict__ Tf,
                                               float2* __restrict__ A) {
    __shared__ short8 Xb[64 * 32];  // 32 KB
    int b = blockIdx.x >> 8;
    int x = blockIdx.x & 255;
    int t = (int)threadIdx.x;
    int w = t >> 6;
    int l = t & 63;
    int q = l >> 4;          // 0..3
    int f4 = l & 15;         // float4 index within a row
    int i0 = f4 * 4;

    const float4* X4 = (const float4*)(X + ((size_t)(b * 256 + x)) * 256 * 64);
#pragma unroll
    for (int h = 0; h < 2; h++) {
        float4 v[8];
#pragma unroll
        for (int n = 0; n < 8; n++) {
            int y = w * 64 + q + 4 * (h * 8 + n);
            v[n] = X4[y * 16 + f4];
        }
        const float* vf = (const float*)v;
        int s = w * 8 + h * 4 + q;
#pragma unroll
        for (int di = 0; di < 4; di++) {
            int i = i0 + di;
            short8 hb;
#pragma unroll
            for (int j = 0; j < 8; j++) hb[j] = (short)f2b(vf[j * 4 + di]);
            Xb[i * 32 + (s ^ (i & 7))] = hb;
        }
    }
    __syncthreads();

    int m16 = l & 15;
    int quad = l >> 4;
    int iRow = w * 16 + m16;
    int isw = iRow & 7;

    f32x4 acc0 = (f32x4){0.f, 0.f, 0.f, 0.f};
    f32x4 acc1 = (f32x4){0.f, 0.f, 0.f, 0.f};
    const unsigned short* T0 = Tf + (size_t)m16 * 256 + quad * 8;
#pragma unroll
    for (int ks = 0; ks < 8; ks++) {
        short8 a0 = *(const short8*)(T0 + ks * 32);
        short8 a1 = *(const short8*)(T0 + 4096 + ks * 32);
        short8 bfrag = Xb[iRow * 32 + ((ks * 4 + quad) ^ isw)];
        acc0 = __builtin_amdgcn_mfma_f32_16x16x32_bf16(a0, bfrag, acc0, 0, 0, 0);
        acc1 = __builtin_amdgcn_mfma_f32_16x16x32_bf16(a1, bfrag, acc1, 0, 0, 0);
    }

    // rows kyc = (mt*16) + quad*4 + r; pairs -> (ky, re/im). A[b][ky][x][i].
    float2* Ab = A + ((size_t)(b * 16) * 256 + x) * 64;
    int ky0 = quad * 2;
    Ab[(size_t)(ky0)     * 16384 + iRow] = make_float2(acc0[0], acc0[1]);
    Ab[(size_t)(ky0 + 1) * 16384 + iRow] = make_float2(acc0[2], acc0[3]);
    Ab[(size_t)(ky0 + 8) * 16384 + iRow] = make_float2(acc1[0], acc1[1]);
    Ab[(size_t)(ky0 + 9) * 16384 + iRow] = make_float2(acc1[2], acc1[3]);
}

// ---------------------------------------------------------------------------
// k_fwd_x (MFMA): C[b,ky,m,i] = (1/256) sum_x A[b][ky][x][i] e^{-i 2pi kx x/256}
// C(64r x 64i) = T2(64 x 512) @ Bs(512 x 64); K = 512 (k = 2x+c, permuted).
__global__ __launch_bounds__(256) void k_fwd_x(const float2* __restrict__ A,
                                               const unsigned short* __restrict__ T2,
                                               float2* __restrict__ C) {
    __shared__ short8 Bs[64 * 64];  // [i][slot], 64 KB
    int bi = blockIdx.x;            // 128 blocks
    int b = bi >> 4;
    int ky = bi & 15;
    int t = (int)threadIdx.x;
    int w = t >> 6, l = t & 63;
    int i2 = (l & 31) * 2;
    int bp = l >> 5;
    const float4* A4 = (const float4*)(A + ((size_t)(b * 16 + ky)) * 256 * 64);
#pragma unroll
    for (int a = 0; a < 8; a++) {
        float4 v[4];
#pragma unroll
        for (int d4 = 0; d4 < 4; d4++) {
            int xx = w * 64 + bp + 8 * a + 2 * d4;
            v[d4] = A4[xx * 32 + (l & 31)];
        }
        int S = w * 16 + bp * 8 + a;
        short8 h0, h1;
        h0[0] = (short)f2b(v[0].x); h0[1] = (short)f2b(v[0].y);
        h0[2] = (short)f2b(v[1].x); h0[3] = (short)f2b(v[1].y);
        h0[4] = (short)f2b(v[2].x); h0[5] = (short)f2b(v[2].y);
        h0[6] = (short)f2b(v[3].x); h0[7] = (short)f2b(v[3].y);
        h1[0] = (short)f2b(v[0].z); h1[1] = (short)f2b(v[0].w);
        h1[2] = (short)f2b(v[1].z); h1[3] = (short)f2b(v[1].w);
        h1[4] = (short)f2b(v[2].z); h1[5] = (short)f2b(v[2].w);
        h1[6] = (short)f2b(v[3].z); h1[7] = (short)f2b(v[3].w);
        Bs[i2 * 64 + (S ^ (i2 & 7))] = h0;
        Bs[(i2 + 1) * 64 + (S ^ ((i2 + 1) & 7))] = h1;
    }
    __syncthreads();

    int m16 = l & 15, quad = l >> 4;
    int iRow = w * 16 + m16;
    int isw = iRow & 7;
    f32x4 acc[4];
#pragma unroll
    for (int mt = 0; mt < 4; mt++) acc[mt] = (f32x4){0.f, 0.f, 0.f, 0.f};
    const unsigned short* Tp = T2 + (size_t)m16 * 512 + quad * 8;
#pragma unroll
    for (int ks = 0; ks < 16; ks++) {
        short8 bfrag = Bs[iRow * 64 + ((ks * 4 + quad) ^ isw)];
#pragma unroll
        for (int mt = 0; mt < 4; mt++) {
            short8 af = *(const short8*)(Tp + mt * 8192 + ks * 32);
            acc[mt] = __builtin_amdgcn_mfma_f32_16x16x32_bf16(af, bfrag, acc[mt], 0, 0, 0);
        }
    }

    // rows r = mt*16 + quad*4 + reg -> m = mt*8 + quad*2 + (reg>>1), c = reg&1
    float2* Cb = C + ((size_t)(b * 16 + ky)) * 32 * 64;
#pragma unroll
    for (int mt = 0; mt < 4; mt++) {
        int m0 = mt * 8 + quad * 2;
        Cb[(size_t)m0 * 64 + iRow]       = make_float2(acc[mt][0], acc[mt][1]);
        Cb[(size_t)(m0 + 1) * 64 + iRow] = make_float2(acc[mt][2], acc[mt][3]);
    }
}

// ---------------------------------------------------------------------------
// k_mix: D[b,ky,m,o] = sum_i C[b,ky,m,i] * w[i,o] (complex)
__global__ __launch_bounds__(256) void k_mix(const float2* __restrict__ C,
                                             const float2* __restrict__ WT,
                                             float2* __restrict__ D) {
    __shared__ float2 Ws[64 * 64];
    __shared__ float2 Cs[8 * 64];
    __shared__ float2 red[4 * 8 * 64];
    int bi = blockIdx.x;
    int ky = bi >> 5;
    int m = bi & 31;
    int t = (int)threadIdx.x;
    const float4* Wsrc = (const float4*)(WT + ((size_t)(m * 16 + ky)) * 4096);
    float4* Wd = (float4*)Ws;
    for (int e = t; e < 2048; e += 256) Wd[e] = Wsrc[e];
    for (int e = t; e < 512; e += 256) {
        int b = e >> 6;
        int i = e & 63;
        Cs[e] = C[(((size_t)b * 16 + ky) * 32 + m) * 64 + i];
    }
    __syncthreads();
    int o = t & 63;
    int ig = t >> 6;
    float dr[8], di[8];
#pragma unroll
    for (int b = 0; b < 8; b++) { dr[b] = 0.f; di[b] = 0.f; }
    for (int i2 = ig * 16; i2 < ig * 16 + 16; i2++) {
        float2 w = Ws[i2 * 64 + o];
#pragma unroll
        for (int b = 0; b < 8; b++) {
            float2 c = Cs[b * 64 + i2];
            dr[b] += c.x * w.x - c.y * w.y;
            di[b] += c.x * w.y + c.y * w.x;
        }
    }
#pragma unroll
    for (int b = 0; b < 8; b++) red[(ig * 8 + b) * 64 + o] = make_float2(dr[b], di[b]);
    __syncthreads();
    for (int e = t; e < 512; e += 256) {
        int b = e >> 6;
        int oo = e & 63;
        float2 s = red[b * 64 + oo];
        float2 s1 = red[(8 + b) * 64 + oo];
        float2 s2 = red[(16 + b) * 64 + oo];
        float2 s3 = red[(24 + b) * 64 + oo];
        D[(((size_t)b * 16 + ky) * 32 + m) * 64 + oo] =
            make_float2((s.x + s1.x) + (s2.x + s3.x), (s.y + s1.y) + (s2.y + s3.y));
    }
}

// ---------------------------------------------------------------------------
// k_inv_x (MFMA): G[b,x,ky,o] = sum_m D[b,ky,m,o] e^{+i 2pi kx x/256}
// G_c(x,o) = A2[c](256 x 64) @ Bd(64 x 64); K = 64 (k = 2m+c, natural order).
__global__ __launch_bounds__(256) void k_inv_x(const float2* __restrict__ D,
                                               const unsigned short* __restrict__ A2,
                                               float2* __restrict__ G) {
    __shared__ short8 Bd[64 * 8];   // [o][slot], 8 KB
    int bi = blockIdx.x;            // 256 blocks
    int b = bi >> 5;
    int ky = (bi >> 1) & 15;
    int xh = bi & 1;
    int t = (int)threadIdx.x;
    int w = t >> 6, l = t & 63;
    const float2* Dp = D + ((size_t)(b * 16 + ky)) * 32 * 64;
    float2 dv[8];
#pragma unroll
    for (int s = 0; s < 8; s++) dv[s] = Dp[(size_t)(w * 8 + s) * 64 + l];
    short8 h0, h1;
    h0[0] = (short)f2b(dv[0].x); h0[1] = (short)f2b(dv[0].y);
    h0[2] = (short)f2b(dv[1].x); h0[3] = (short)f2b(dv[1].y);
    h0[4] = (short)f2b(dv[2].x); h0[5] = (short)f2b(dv[2].y);
    h0[6] = (short)f2b(dv[3].x); h0[7] = (short)f2b(dv[3].y);
    h1[0] = (short)f2b(dv[4].x); h1[1] = (short)f2b(dv[4].y);
    h1[2] = (short)f2b(dv[5].x); h1[3] = (short)f2b(dv[5].y);
    h1[4] = (short)f2b(dv[6].x); h1[5] = (short)f2b(dv[6].y);
    h1[6] = (short)f2b(dv[7].x); h1[7] = (short)f2b(dv[7].y);
    int sl = l & 7;
    Bd[l * 8 + ((2 * w) ^ sl)]     = h0;
    Bd[l * 8 + ((2 * w + 1) ^ sl)] = h1;
    __syncthreads();

    int m16 = l & 15, quad = l >> 4;
    int x0 = xh * 128 + w * 32;
    f32x4 acc[2][4][2];
#pragma unroll
    for (int mt = 0; mt < 2; mt++)
#pragma unroll
        for (int nt = 0; nt < 4; nt++)
#pragma unroll
            for (int c = 0; c < 2; c++) acc[mt][nt][c] = (f32x4){0.f, 0.f, 0.f, 0.f};

#pragma unroll
    for (int ks = 0; ks < 2; ks++) {
        short8 ar[2], ai[2];
#pragma unroll
        for (int mt = 0; mt < 2; mt++) {
            int xr = x0 + mt * 16 + m16;
            ar[mt] = *(const short8*)(A2 + (size_t)xr * 64 + ks * 32 + quad * 8);
            ai[mt] = *(const short8*)(A2 + 16384 + (size_t)xr * 64 + ks * 32 + quad * 8);
        }
#pragma unroll
        for (int nt = 0; nt < 4; nt++) {
            int o = nt * 16 + m16;
            short8 bf = Bd[o * 8 + ((ks * 4 + quad) ^ (o & 7))];
#pragma unroll
            for (int mt = 0; mt < 2; mt++) {
                acc[mt][nt][0] = __builtin_amdgcn_mfma_f32_16x16x32_bf16(ar[mt], bf, acc[mt][nt][0], 0, 0, 0);
                acc[mt][nt][1] = __builtin_amdgcn_mfma_f32_16x16x32_bf16(ai[mt], bf, acc[mt][nt][1], 0, 0, 0);
            }
        }
    }

#pragma unroll
    for (int mt = 0; mt < 2; mt++)
#pragma unroll
        for (int nt = 0; nt < 4; nt++) {
            int o = nt * 16 + m16;
#pragma unroll
            for (int r = 0; r < 4; r++) {
                int x = x0 + mt * 16 + quad * 4 + r;
                G[((size_t)(b * 256 + x) * 16 + ky) * 64 + o] =
                    make_float2(acc[mt][nt][0][r], acc[mt][nt][1][r]);
            }
        }
}

// ---------------------------------------------------------------------------
// k_out: MFMA GEMM, K=96: out[y][o] = silu(X[y][:]Wres + T[y][:]Gfold + b)
__global__ __launch_bounds__(256) void k_out(const float* __restrict__ X,
                                             const float2* __restrict__ G,
                                             const unsigned short* __restrict__ WbT,
                                             const unsigned short* __restrict__ Tg,
                                             const float* __restrict__ bres,
                                             float* __restrict__ out) {
    __shared__ unsigned short Bsp[64 * 32];  // Gfold^T: [o][kk]
    int b = blockIdx.x >> 8;
    int x = blockIdx.x & 255;
    int t = (int)threadIdx.x;

    const float2* Gp = G + ((size_t)(b * 256 + x)) * 16 * 64;
    for (int e = t; e < 1024; e += 256) {
        int ky = e >> 6, o = e & 63;
        float2 g = Gp[e];
        float sc = (ky == 0) ? (1.0f / 256.0f) : (2.0f / 256.0f);
        Bsp[o * 32 + 2 * ky]     = f2b(g.x * sc);
        Bsp[o * 32 + 2 * ky + 1] = f2b(g.y * sc);
    }
    __syncthreads();

    int w = t >> 6;
    int l = t & 63;
    int m16 = l & 15;
    int quad = l >> 4;

    short8 bw0[4], bw1[4], bs[4];
    float br[4];
#pragma unroll
    for (int nt = 0; nt < 4; nt++) {
        int o = nt * 16 + m16;
        bw0[nt] = *(const short8*)(WbT + o * 64 + quad * 8);
        bw1[nt] = *(const short8*)(WbT + o * 64 + 32 + quad * 8);
        bs[nt]  = *(const short8*)(Bsp + o * 32 + quad * 8);
        br[nt]  = bres[o];
    }

    const float* Xrow = X + ((size_t)(b * 256 + x)) * 256 * 64;
    float* orow = out + ((size_t)(b * 256 + x)) * 256 * 64;

    f32x4 acc[4][4];
#pragma unroll
    for (int mt = 0; mt < 4; mt++)
#pragma unroll
        for (int nt = 0; nt < 4; nt++) acc[mt][nt] = (f32x4){0.f, 0.f, 0.f, 0.f};

#pragma unroll
    for (int mt = 0; mt < 4; mt++) {
        int y = w * 64 + mt * 16 + m16;
        const float4* xp = (const float4*)(Xrow + (size_t)y * 64 + quad * 8);
        float4 v0 = xp[0], v1 = xp[1];
        const float4* xq = (const float4*)(Xrow + (size_t)y * 64 + 32 + quad * 8);
        float4 v2 = xq[0], v3 = xq[1];
        short8 a0, a1;
        a0[0] = (short)f2b(v0.x); a0[1] = (short)f2b(v0.y);
        a0[2] = (short)f2b(v0.z); a0[3] = (short)f2b(v0.w);
        a0[4] = (short)f2b(v1.x); a0[5] = (short)f2b(v1.y);
        a0[6] = (short)f2b(v1.z); a0[7] = (short)f2b(v1.w);
        a1[0] = (short)f2b(v2.x); a1[1] = (short)f2b(v2.y);
        a1[2] = (short)f2b(v2.z); a1[3] = (short)f2b(v2.w);
        a1[4] = (short)f2b(v3.x); a1[5] = (short)f2b(v3.y);
        a1[6] = (short)f2b(v3.z); a1[7] = (short)f2b(v3.w);
        short8 aT = *(const short8*)(Tg + (size_t)y * 32 + quad * 8);
#pragma unroll
        for (int nt = 0; nt < 4; nt++) {
            acc[mt][nt] = __builtin_amdgcn_mfma_f32_16x16x32_bf16(a0, bw0[nt], acc[mt][nt], 0, 0, 0);
            acc[mt][nt] = __builtin_amdgcn_mfma_f32_16x16x32_bf16(a1, bw1[nt], acc[mt][nt], 0, 0, 0);
            acc[mt][nt] = __builtin_amdgcn_mfma_f32_16x16x32_bf16(aT, bs[nt],  acc[mt][nt], 0, 0, 0);
        }
    }

#pragma unroll
    for (int mt = 0; mt < 4; mt++) {
#pragma unroll
        for (int nt = 0; nt < 4; nt++) {
            int o = nt * 16 + m16;
#pragma unroll
            for (int r = 0; r < 4; r++) {
                int y = w * 64 + mt * 16 + quad * 4 + r;
                float v = acc[mt][nt][r] + br[nt];
                float sg = __builtin_amdgcn_rcpf(1.0f + __expf(-v));
                orow[(size_t)y * 64 + o] = v * sg;
            }
        }
    }
}

extern "C" void kernel_launch(void* const* d_in, const int* in_sizes, int n_in,
                              void* d_out, int out_size, void* d_ws, size_t ws_size,
                              hipStream_t stream) {
    const float* X    = (const float*)d_in[0];
    const float* Wres = (const float*)d_in[1];
    const float* bres = (const float*)d_in[2];
    const float* fw0  = (const float*)d_in[3];
    const float* fw1  = (const float*)d_in[4];
    float* out = (float*)d_out;

    // workspace (float2 units): A/G 2097152 | C 262144 | D 262144 | WT 2097152
    float2* A  = (float2*)d_ws;
    float2* C  = A + 2097152;
    float2* D  = C + 262144;
    float2* WT = D + 262144;
    float2* G  = A;  // reuse A after k_fwd_x consumes it
    // D-region overlay (free until k_mix): Tf2 8192 ush + T2 32768 ush = 80 KB
    unsigned short* Tf2 = (unsigned short*)D;
    unsigned short* T2  = Tf2 + 8192;
    // C-region overlay (free after k_mix): WbT 4096 + Tg 8192 + A2 32768 ush
    unsigned short* WbT = (unsigned short*)C;
    unsigned short* Tg  = WbT + 4096;
    unsigned short* A2  = Tg + 8192;

    k_wt<<<512, 256, 0, stream>>>(fw0, fw1, WT);
    k_tf<<<160, 256, 0, stream>>>(Tf2, T2);
    k_fwd_y<<<NB * 256, 256, 0, stream>>>(X, Tf2, A);
    k_fwd_x<<<128, 256, 0, stream>>>(A, T2, C);
    k_mix<<<16 * 32, 256, 0, stream>>>(C, WT, D);
    k_prep<<<176, 256, 0, stream>>>(Wres, WbT, Tg, A2);  // after k_mix (C reuse)
    k_inv_x<<<256, 256, 0, stream>>>(D, A2, G);
    k_out<<<NB * 256, 256, 0, stream>>>(X, G, WbT, Tg, bres, out);
}

// Round 4
// 310.759 us; speedup vs baseline: 1.5184x; 1.0444x over previous
//
#include <hip/hip_runtime.h>
#include <math.h>

#define RDIM 256
#define CIN 64
#define COUT 64
#define MODES 16
#define NB 8

typedef short short8 __attribute__((ext_vector_type(8)));
typedef float f32x4 __attribute__((ext_vector_type(4)));

// f32 -> bf16 bits, round-to-nearest-even
__device__ __forceinline__ unsigned short f2b(float f) {
    unsigned u = __builtin_bit_cast(unsigned, f);
    unsigned r = (u + 0x7FFFu + ((u >> 16) & 1u)) >> 16;
    return (unsigned short)r;
}

// ---------------------------------------------------------------------------
// k_tab: all twiddle/weight tables (dedicated region -> no overlay hazards).
//  Tf2[kyc(32)][k(256)]: forward-y twiddles (k-permuted, see r2).
//  T2[r(64)][k(512)]: forward-x twiddles, 1/256 folded (k-permuted).
//  WbT[o][k]: bf16 Wres^T.  Tg[y][kk]: irfft y-twiddles.
//  A2[comp(2)][x(256)][k(64)]: inverse-x twiddles.
__global__ __launch_bounds__(256) void k_tab(const float* __restrict__ Wres,
                                             unsigned short* __restrict__ Tf2,
                                             unsigned short* __restrict__ T2,
                                             unsigned short* __restrict__ WbT,
                                             unsigned short* __restrict__ Tg,
                                             unsigned short* __restrict__ A2) {
    int e = blockIdx.x * 256 + (int)threadIdx.x;  // [0, 86016)
    if (e < 8192) {
        int kyc = e >> 8, k = e & 255;
        int S = k >> 3, j = k & 7;
        int w = S >> 3, h = (S >> 2) & 1, q = S & 3;
        int y = w * 64 + q + 4 * (h * 8 + j);
        int ky = kyc >> 1;
        int p = (ky * y) & 255;
        float ang = (float)p * (float)(2.0 * M_PI / 256.0);
        float sz, cz;
        sincosf(ang, &sz, &cz);
        Tf2[e] = f2b((kyc & 1) ? -sz : cz);
    } else if (e < 40960) {
        int f = e - 8192;  // [0, 32768)
        int r = f >> 9, k = f & 511;
        int S = k >> 3, j = k & 7;
        int w = S >> 4, bp = (S >> 3) & 1, a = S & 7;
        int d = j >> 1, c = j & 1;
        int x = w * 64 + bp + 8 * a + 2 * d;
        int m = r >> 1, cc = r & 1;
        int kx = (m < 16) ? m : (m + 224);
        int p = (kx * x) & 255;
        float ang = (float)p * (float)(2.0 * M_PI / 256.0);
        float sz, cz;
        sincosf(ang, &sz, &cz);
        float val = (cc == 0) ? (c ? sz : cz) : (c ? cz : -sz);
        T2[f] = f2b(val * (1.0f / 256.0f));
    } else if (e < 45056) {
        int f = e - 40960;  // [0, 4096)
        int o = f >> 6, k = f & 63;
        WbT[o * 64 + k] = f2b(Wres[k * 64 + o]);
    } else if (e < 53248) {
        int f = e - 45056;  // [0, 8192)
        int y = f >> 5, kk = f & 31, ky = kk >> 1;
        int p = (ky * y) & 255;
        float ang = (float)p * (float)(2.0 * M_PI / 256.0);
        float sz, cz;
        sincosf(ang, &sz, &cz);
        Tg[f] = f2b((kk & 1) ? -sz : cz);
    } else {
        int f = e - 53248;  // [0, 32768)
        int comp = f >> 14, g = f & 16383;
        int x = g >> 6, k = g & 63;
        int m = k >> 1, c = k & 1;
        int kx = (m < 16) ? m : (m + 224);
        int p = (kx * x) & 255;
        float ang = (float)p * (float)(2.0 * M_PI / 256.0);
        float sz, cz;
        sincosf(ang, &sz, &cz);
        float val = (comp == 0) ? (c ? -sz : cz) : (c ? cz : sz);
        A2[f] = f2b(val);
    }
}

// ---------------------------------------------------------------------------
// k_wt: fw0/fw1 [i,o,mx,ky,2] -> WTb bf16 [(m*16+ky)][var(2)][oct(16)][o(64)][j(8)]
// var0 (D_re): k=2i+0 -> wr, 2i+1 -> -wi.  var1 (D_im): k=2i+0 -> wi, 2i+1 -> wr.
// Block = (arr, i-quad, o-16run, mx-half): stages [64 pairs][128 q] f32 via LDS.
__global__ __launch_bounds__(256) void k_wt(const float* __restrict__ fw0,
                                            const float* __restrict__ fw1,
                                            unsigned short* __restrict__ WTb) {
    __shared__ float2 Ls[64 * 134];  // [io][q], pad 128->134 for bank spread
    int bi = blockIdx.x;             // 256
    int arr = bi >> 7;
    int iq = (bi >> 3) & 15;         // i0 = iq*4; oct = iq
    int oq = (bi >> 1) & 3;          // o0 = oq*16
    int h = bi & 1;                  // mx-half
    int i0 = iq * 4, o0 = oq * 16;
    const float4* fw4 = (const float4*)(arr ? fw1 : fw0);
    int t = (int)threadIdx.x;
    // load: 64 pairs x 64 float4 (=128 float2 of (mx,ky), the h-half)
#pragma unroll
    for (int n = 0; n < 16; n++) {
        int idx = n * 256 + t;
        int io = idx >> 6, fi = idx & 63;
        int i_loc = io >> 4, o_loc = io & 15;
        float4 v = fw4[(size_t)((i0 + i_loc) * 64 + o0 + o_loc) * 128 + h * 64 + fi];
        ((float4*)Ls)[io * 67 + fi] = v;
    }
    __syncthreads();
    // write: 4096 short8 units = var(2) x mm(8) x ky(16) x o_loc(16)
#pragma unroll
    for (int n = 0; n < 16; n++) {
        int u = n * 256 + t;
        int o_loc = u & 15, ky = (u >> 4) & 15, mm = (u >> 8) & 7, var = u >> 11;
        int qL = mm * 16 + ky;
        short8 hh;
#pragma unroll
        for (int j = 0; j < 8; j++) {
            int i_loc = j >> 1, c = j & 1;
            float2 wv = Ls[(i_loc * 16 + o_loc) * 134 + qL];
            float val = var ? (c ? wv.x : wv.y) : (c ? -wv.y : wv.x);
            hh[j] = (short)f2b(val);
        }
        int m = arr * 16 + h * 8 + mm;
        int o = o0 + o_loc;
        *(short8*)(WTb + (size_t)(m * 16 + ky) * 16384 + var * 8192 + iq * 512 + o * 8) = hh;
    }
}

// ---------------------------------------------------------------------------
// k_fwd_y (MFMA): A[b][ky][x][i] = sum_y X e^{-2pi i ky y/256}; also emits
// Xbf[b,x][y][i] bf16 (row-major) for k_out's direct short8 A-frag loads.
__global__ __launch_bounds__(256) void k_fwd_y(const float* __restrict__ X,
                                               const unsigned short* __restrict__ Tf,
                                               float2* __restrict__ A,
                                               unsigned short* __restrict__ Xbf) {
    __shared__ short8 Xb[64 * 32];  // 32 KB
    int b = blockIdx.x >> 8;
    int x = blockIdx.x & 255;
    int t = (int)threadIdx.x;
    int w = t >> 6;
    int l = t & 63;
    int q = l >> 4;          // 0..3
    int f4 = l & 15;
    int i0 = f4 * 4;

    const float4* X4 = (const float4*)(X + ((size_t)(b * 256 + x)) * 256 * 64);
    unsigned short* Xrow = Xbf + ((size_t)(b * 256 + x)) * 16384;
#pragma unroll
    for (int h = 0; h < 2; h++) {
        float4 v[8];
#pragma unroll
        for (int n = 0; n < 8; n++) {
            int y = w * 64 + q + 4 * (h * 8 + n);
            v[n] = X4[y * 16 + f4];
        }
        // Xbf stores (values CSE with the LDS packing below)
#pragma unroll
        for (int n = 0; n < 8; n++) {
            int y = w * 64 + q + 4 * (h * 8 + n);
            *(ushort4*)(Xrow + (size_t)y * 64 + i0) =
                make_ushort4(f2b(v[n].x), f2b(v[n].y), f2b(v[n].z), f2b(v[n].w));
        }
        const float* vf = (const float*)v;
        int s = w * 8 + h * 4 + q;
#pragma unroll
        for (int di = 0; di < 4; di++) {
            int i = i0 + di;
            short8 hb;
#pragma unroll
            for (int j = 0; j < 8; j++) hb[j] = (short)f2b(vf[j * 4 + di]);
            Xb[i * 32 + (s ^ (i & 7))] = hb;
        }
    }
    __syncthreads();

    int m16 = l & 15;
    int quad = l >> 4;
    int iRow = w * 16 + m16;
    int isw = iRow & 7;

    f32x4 acc0 = (f32x4){0.f, 0.f, 0.f, 0.f};
    f32x4 acc1 = (f32x4){0.f, 0.f, 0.f, 0.f};
    const unsigned short* T0 = Tf + (size_t)m16 * 256 + quad * 8;
#pragma unroll
    for (int ks = 0; ks < 8; ks++) {
        short8 a0 = *(const short8*)(T0 + ks * 32);
        short8 a1 = *(const short8*)(T0 + 4096 + ks * 32);
        short8 bfrag = Xb[iRow * 32 + ((ks * 4 + quad) ^ isw)];
        acc0 = __builtin_amdgcn_mfma_f32_16x16x32_bf16(a0, bfrag, acc0, 0, 0, 0);
        acc1 = __builtin_amdgcn_mfma_f32_16x16x32_bf16(a1, bfrag, acc1, 0, 0, 0);
    }

    float2* Ab = A + ((size_t)(b * 16) * 256 + x) * 64;
    int ky0 = quad * 2;
    Ab[(size_t)(ky0)     * 16384 + iRow] = make_float2(acc0[0], acc0[1]);
    Ab[(size_t)(ky0 + 1) * 16384 + iRow] = make_float2(acc0[2], acc0[3]);
    Ab[(size_t)(ky0 + 8) * 16384 + iRow] = make_float2(acc1[0], acc1[1]);
    Ab[(size_t)(ky0 + 9) * 16384 + iRow] = make_float2(acc1[2], acc1[3]);
}

// ---------------------------------------------------------------------------
// k_fwd_x (MFMA): C[b,ky,m,i] = (1/256) sum_x A[b][ky][x][i] e^{-i 2pi kx x/256}
// 256 blocks (i split in halves) for full-CU occupancy. K = 512.
__global__ __launch_bounds__(256) void k_fwd_x(const float2* __restrict__ A,
                                               const unsigned short* __restrict__ T2,
                                               float2* __restrict__ C) {
    __shared__ short8 Bs[32 * 64];  // 32 KB
    int bi = blockIdx.x;            // 256
    int b = bi >> 5;
    int ky = (bi >> 1) & 15;
    int ih = bi & 1;
    int t = (int)threadIdx.x;
    int w = t >> 6, l = t & 63;
    int ip = l & 15;
    int bp = (l >> 4) & 1;
    int ab = l >> 5;
    const float4* A4 = (const float4*)(A + ((size_t)(b * 16 + ky)) * 16384);
#pragma unroll
    for (int aa = 0; aa < 4; aa++) {
        int a = ab * 4 + aa;
        float4 v[4];
#pragma unroll
        for (int d4 = 0; d4 < 4; d4++) {
            int xx = w * 64 + bp + 8 * a + 2 * d4;
            v[d4] = A4[xx * 32 + ih * 16 + ip];
        }
        int S = w * 16 + bp * 8 + a;
        short8 h0, h1;
        h0[0] = (short)f2b(v[0].x); h0[1] = (short)f2b(v[0].y);
        h0[2] = (short)f2b(v[1].x); h0[3] = (short)f2b(v[1].y);
        h0[4] = (short)f2b(v[2].x); h0[5] = (short)f2b(v[2].y);
        h0[6] = (short)f2b(v[3].x); h0[7] = (short)f2b(v[3].y);
        h1[0] = (short)f2b(v[0].z); h1[1] = (short)f2b(v[0].w);
        h1[2] = (short)f2b(v[1].z); h1[3] = (short)f2b(v[1].w);
        h1[4] = (short)f2b(v[2].z); h1[5] = (short)f2b(v[2].w);
        h1[6] = (short)f2b(v[3].z); h1[7] = (short)f2b(v[3].w);
        int iL0 = ip * 2, iL1 = iL0 + 1;
        Bs[iL0 * 64 + (S ^ (iL0 & 7))] = h0;
        Bs[iL1 * 64 + (S ^ (iL1 & 7))] = h1;
    }
    __syncthreads();

    int m16 = l & 15, quad = l >> 4;
    f32x4 acc[2];
    acc[0] = (f32x4){0.f, 0.f, 0.f, 0.f};
    acc[1] = (f32x4){0.f, 0.f, 0.f, 0.f};
    const unsigned short* Tp = T2 + (size_t)(w * 16 + m16) * 512 + quad * 8;
#pragma unroll
    for (int ks = 0; ks < 16; ks++) {
        short8 af = *(const short8*)(Tp + ks * 32);
#pragma unroll
        for (int nt = 0; nt < 2; nt++) {
            int iL = nt * 16 + m16;
            short8 bfr = Bs[iL * 64 + ((ks * 4 + quad) ^ (iL & 7))];
            acc[nt] = __builtin_amdgcn_mfma_f32_16x16x32_bf16(af, bfr, acc[nt], 0, 0, 0);
        }
    }

    float2* Cb = C + ((size_t)(b * 16 + ky)) * 2048;
    int m0 = w * 8 + quad * 2;
#pragma unroll
    for (int nt = 0; nt < 2; nt++) {
        int ig = ih * 32 + nt * 16 + m16;
        Cb[(size_t)m0 * 64 + ig]       = make_float2(acc[nt][0], acc[nt][1]);
        Cb[(size_t)(m0 + 1) * 64 + ig] = make_float2(acc[nt][2], acc[nt][3]);
    }
}

// ---------------------------------------------------------------------------
// k_mix (MFMA): D[b,ky,m,o] = sum_i C[b,ky,m,i]*w[i,o] (complex) as real GEMM
// M=16 (8 b, rows 8-15 discarded) x N=64 x K=128 (k=2i+c). B from WTb direct.
__global__ __launch_bounds__(256) void k_mix(const float2* __restrict__ C,
                                             const unsigned short* __restrict__ WTb,
                                             float2* __restrict__ D) {
    __shared__ float Csf[8 * 132];  // [b][k(128)] floats, pad 132
    int bi = blockIdx.x;            // 512
    int ky = bi >> 5, m = bi & 31;
    int t = (int)threadIdx.x;
    {
        int bq = t >> 5;
        int e = t & 31;
        const float4* src = (const float4*)(C + (((size_t)bq * 16 + ky) * 32 + m) * 64);
        ((float4*)Csf)[bq * 33 + e] = src[e];
    }
    __syncthreads();
    int w = t >> 6, l = t & 63;
    int var = w >> 1, ntb = (w & 1) * 2;
    int m16 = l & 15, quad = l >> 4;
    const unsigned short* Wp = WTb + (size_t)(m * 16 + ky) * 16384 + var * 8192;
    const float* cp0 = Csf + (m16 & 7) * 132 + quad * 8;
    f32x4 acc[2];
    acc[0] = (f32x4){0.f, 0.f, 0.f, 0.f};
    acc[1] = (f32x4){0.f, 0.f, 0.f, 0.f};
#pragma unroll
    for (int ks = 0; ks < 4; ks++) {
        const float* cp = cp0 + ks * 32;
        short8 af;
#pragma unroll
        for (int j = 0; j < 8; j++) af[j] = (short)f2b(cp[j]);
        int oct = ks * 4 + quad;
#pragma unroll
        for (int n2 = 0; n2 < 2; n2++) {
            int o = (ntb + n2) * 16 + m16;
            short8 bfr = *(const short8*)(Wp + oct * 512 + o * 8);
            acc[n2] = __builtin_amdgcn_mfma_f32_16x16x32_bf16(af, bfr, acc[n2], 0, 0, 0);
        }
    }
    if (quad < 2) {
#pragma unroll
        for (int n2 = 0; n2 < 2; n2++) {
            int o = (ntb + n2) * 16 + m16;
#pragma unroll
            for (int r = 0; r < 4; r++) {
                int bb = quad * 4 + r;
                float* dp = (float*)&D[(((size_t)bb * 16 + ky) * 32 + m) * 64 + o];
                dp[var] = acc[n2][r];
            }
        }
    }
}

// ---------------------------------------------------------------------------
// k_inv_x (MFMA): G[b,x,ky,o] = sum_m D[b,ky,m,o] e^{+i 2pi kx x/256}
__global__ __launch_bounds__(256) void k_inv_x(const float2* __restrict__ D,
                                               const unsigned short* __restrict__ A2,
                                               float2* __restrict__ G) {
    __shared__ short8 Bd[64 * 8];   // 8 KB
    int bi = blockIdx.x;            // 256
    int b = bi >> 5;
    int ky = (bi >> 1) & 15;
    int xh = bi & 1;
    int t = (int)threadIdx.x;
    int w = t >> 6, l = t & 63;
    const float2* Dp = D + ((size_t)(b * 16 + ky)) * 2048;
    float2 dv[8];
#pragma unroll
    for (int s = 0; s < 8; s++) dv[s] = Dp[(size_t)(w * 8 + s) * 64 + l];
    short8 h0, h1;
    h0[0] = (short)f2b(dv[0].x); h0[1] = (short)f2b(dv[0].y);
    h0[2] = (short)f2b(dv[1].x); h0[3] = (short)f2b(dv[1].y);
    h0[4] = (short)f2b(dv[2].x); h0[5] = (short)f2b(dv[2].y);
    h0[6] = (short)f2b(dv[3].x); h0[7] = (short)f2b(dv[3].y);
    h1[0] = (short)f2b(dv[4].x); h1[1] = (short)f2b(dv[4].y);
    h1[2] = (short)f2b(dv[5].x); h1[3] = (short)f2b(dv[5].y);
    h1[4] = (short)f2b(dv[6].x); h1[5] = (short)f2b(dv[6].y);
    h1[6] = (short)f2b(dv[7].x); h1[7] = (short)f2b(dv[7].y);
    int sl = l & 7;
    Bd[l * 8 + ((2 * w) ^ sl)]     = h0;
    Bd[l * 8 + ((2 * w + 1) ^ sl)] = h1;
    __syncthreads();

    int m16 = l & 15, quad = l >> 4;
    int x0 = xh * 128 + w * 32;
    f32x4 acc[2][4][2];
#pragma unroll
    for (int mt = 0; mt < 2; mt++)
#pragma unroll
        for (int nt = 0; nt < 4; nt++)
#pragma unroll
            for (int c = 0; c < 2; c++) acc[mt][nt][c] = (f32x4){0.f, 0.f, 0.f, 0.f};

#pragma unroll
    for (int ks = 0; ks < 2; ks++) {
        short8 ar[2], ai[2];
#pragma unroll
        for (int mt = 0; mt < 2; mt++) {
            int xr = x0 + mt * 16 + m16;
            ar[mt] = *(const short8*)(A2 + (size_t)xr * 64 + ks * 32 + quad * 8);
            ai[mt] = *(const short8*)(A2 + 16384 + (size_t)xr * 64 + ks * 32 + quad * 8);
        }
#pragma unroll
        for (int nt = 0; nt < 4; nt++) {
            int o = nt * 16 + m16;
            short8 bf = Bd[o * 8 + ((ks * 4 + quad) ^ (o & 7))];
#pragma unroll
            for (int mt = 0; mt < 2; mt++) {
                acc[mt][nt][0] = __builtin_amdgcn_mfma_f32_16x16x32_bf16(ar[mt], bf, acc[mt][nt][0], 0, 0, 0);
                acc[mt][nt][1] = __builtin_amdgcn_mfma_f32_16x16x32_bf16(ai[mt], bf, acc[mt][nt][1], 0, 0, 0);
            }
        }
    }

#pragma unroll
    for (int mt = 0; mt < 2; mt++)
#pragma unroll
        for (int nt = 0; nt < 4; nt++) {
            int o = nt * 16 + m16;
#pragma unroll
            for (int r = 0; r < 4; r++) {
                int x = x0 + mt * 16 + quad * 4 + r;
                G[((size_t)(b * 256 + x) * 16 + ky) * 64 + o] =
                    make_float2(acc[mt][nt][0][r], acc[mt][nt][1][r]);
            }
        }
}

// ---------------------------------------------------------------------------
// k_out: MFMA GEMM, K=96: out[y][o] = silu(Xbf[y][:]Wres + T[y][:]Gfold + b)
// A-frags now direct short8 loads from Xbf (no f2b, half the X traffic).
__global__ __launch_bounds__(256) void k_out(const unsigned short* __restrict__ Xbf,
                                             const float2* __restrict__ G,
                                             const unsigned short* __restrict__ WbT,
                                             const unsigned short* __restrict__ Tg,
                                             const float* __restrict__ bres,
                                             float* __restrict__ out) {
    __shared__ unsigned short Bsp[64 * 32];  // Gfold^T: [o][kk]
    int b = blockIdx.x >> 8;
    int x = blockIdx.x & 255;
    int t = (int)threadIdx.x;

    const float2* Gp = G + ((size_t)(b * 256 + x)) * 16 * 64;
    for (int e = t; e < 1024; e += 256) {
        int ky = e >> 6, o = e & 63;
        float2 g = Gp[e];
        float sc = (ky == 0) ? (1.0f / 256.0f) : (2.0f / 256.0f);
        Bsp[o * 32 + 2 * ky]     = f2b(g.x * sc);
        Bsp[o * 32 + 2 * ky + 1] = f2b(g.y * sc);
    }
    __syncthreads();

    int w = t >> 6;
    int l = t & 63;
    int m16 = l & 15;
    int quad = l >> 4;

    short8 bw0[4], bw1[4], bs[4];
    float br[4];
#pragma unroll
    for (int nt = 0; nt < 4; nt++) {
        int o = nt * 16 + m16;
        bw0[nt] = *(const short8*)(WbT + o * 64 + quad * 8);
        bw1[nt] = *(const short8*)(WbT + o * 64 + 32 + quad * 8);
        bs[nt]  = *(const short8*)(Bsp + o * 32 + quad * 8);
        br[nt]  = bres[o];
    }

    const unsigned short* Xrow = Xbf + ((size_t)(b * 256 + x)) * 16384;
    float* orow = out + ((size_t)(b * 256 + x)) * 256 * 64;

    f32x4 acc[4][4];
#pragma unroll
    for (int mt = 0; mt < 4; mt++)
#pragma unroll
        for (int nt = 0; nt < 4; nt++) acc[mt][nt] = (f32x4){0.f, 0.f, 0.f, 0.f};

#pragma unroll
    for (int mt = 0; mt < 4; mt++) {
        int y = w * 64 + mt * 16 + m16;
        short8 a0 = *(const short8*)(Xrow + (size_t)y * 64 + quad * 8);
        short8 a1 = *(const short8*)(Xrow + (size_t)y * 64 + 32 + quad * 8);
        short8 aT = *(const short8*)(Tg + (size_t)y * 32 + quad * 8);
#pragma unroll
        for (int nt = 0; nt < 4; nt++) {
            acc[mt][nt] = __builtin_amdgcn_mfma_f32_16x16x32_bf16(a0, bw0[nt], acc[mt][nt], 0, 0, 0);
            acc[mt][nt] = __builtin_amdgcn_mfma_f32_16x16x32_bf16(a1, bw1[nt], acc[mt][nt], 0, 0, 0);
            acc[mt][nt] = __builtin_amdgcn_mfma_f32_16x16x32_bf16(aT, bs[nt],  acc[mt][nt], 0, 0, 0);
        }
    }

#pragma unroll
    for (int mt = 0; mt < 4; mt++) {
#pragma unroll
        for (int nt = 0; nt < 4; nt++) {
            int o = nt * 16 + m16;
#pragma unroll
            for (int r = 0; r < 4; r++) {
                int y = w * 64 + mt * 16 + quad * 4 + r;
                float v = acc[mt][nt][r] + br[nt];
                float sg = __builtin_amdgcn_rcpf(1.0f + __expf(-v));
                orow[(size_t)y * 64 + o] = v * sg;
            }
        }
    }
}

extern "C" void kernel_launch(void* const* d_in, const int* in_sizes, int n_in,
                              void* d_out, int out_size, void* d_ws, size_t ws_size,
                              hipStream_t stream) {
    const float* X    = (const float*)d_in[0];
    const float* Wres = (const float*)d_in[1];
    const float* bres = (const float*)d_in[2];
    const float* fw0  = (const float*)d_in[3];
    const float* fw1  = (const float*)d_in[4];
    float* out = (float*)d_out;

    // workspace: A/G 16MB | C 2MB | D 2MB | WTb 16MB | Xbf 64MB | tables 160KB
    float2* A = (float2*)d_ws;
    float2* C = A + 2097152;
    float2* D = C + 262144;
    unsigned short* WTb = (unsigned short*)(D + 262144);
    unsigned short* Xbf = WTb + 8388608;
    unsigned short* Tf2 = Xbf + 33554432;
    unsigned short* T2  = Tf2 + 8192;
    unsigned short* WbT = T2 + 32768;
    unsigned short* Tg  = WbT + 4096;
    unsigned short* A2  = Tg + 8192;
    float2* G = A;  // reuse A after k_fwd_x consumes it

    k_tab<<<336, 256, 0, stream>>>(Wres, Tf2, T2, WbT, Tg, A2);
    k_wt<<<256, 256, 0, stream>>>(fw0, fw1, WTb);
    k_fwd_y<<<NB * 256, 256, 0, stream>>>(X, Tf2, A, Xbf);
    k_fwd_x<<<256, 256, 0, stream>>>(A, T2, C);
    k_mix<<<512, 256, 0, stream>>>(C, WTb, D);
    k_inv_x<<<256, 256, 0, stream>>>(D, A2, G);
    k_out<<<NB * 256, 256, 0, stream>>>(Xbf, G, WbT, Tg, bres, out);
}